// Round 1
// baseline (130.897 us; speedup 1.0000x reference)
//
#include <hip/hip_runtime.h>

// Problem constants
#define BATCH 16384
#define KEYD  64
#define DDIM  128
#define UDIM  128
#define MODES 32

typedef __attribute__((ext_vector_type(8))) short bf16x8;   // 8 bf16 in 4 VGPRs
typedef __attribute__((ext_vector_type(4))) float f32x4;

__device__ __forceinline__ unsigned short f2bf(float f) {
  unsigned u = __float_as_uint(f);
  // round-to-nearest-even bf16
  unsigned r = (u + 0x7FFFu + ((u >> 16) & 1u)) >> 16;
  return (unsigned short)r;
}

__device__ __forceinline__ void gld_lds16(const void* g, void* l) {
  __builtin_amdgcn_global_load_lds(
      (const __attribute__((address_space(1))) unsigned int*)g,
      (__attribute__((address_space(3))) unsigned int*)l, 16, 0, 0);
}

// ---------------------------------------------------------------------------
// Kernel 1: per-row softmax similarity + x -> bf16 cast.
// One half-wave (32 lanes) per batch row: lane m computes dist(b, mode m),
// softmax across the 32 lanes via shfl_xor (<32 masks stay in the half-wave).
// ---------------------------------------------------------------------------
__global__ __launch_bounds__(256) void prep_sim_x(
    const float* __restrict__ key, const float* __restrict__ x,
    const float* __restrict__ sens, const float* __restrict__ keys_map,
    float* __restrict__ sim, unsigned short* __restrict__ x16) {
  __shared__ float kmT[KEYD * MODES];  // [k][m] so lane-m reads are bank-consecutive
  int t = threadIdx.x;
  for (int i = t; i < MODES * KEYD; i += 256) {
    int m = i >> 6, k = i & 63;
    kmT[k * MODES + m] = keys_map[i];
  }
  __syncthreads();

  int lane = t & 63;
  int wave = t >> 6;
  int half = lane >> 5;
  int m = lane & 31;
  int row = blockIdx.x * 8 + wave * 2 + half;

  const float* krow = key + (long)row * KEYD;
  float d2 = 0.f;
  #pragma unroll
  for (int k = 0; k < KEYD; ++k) {
    float diff = krow[k] - kmT[k * MODES + m];
    d2 += diff * diff;
  }
  float logit = sens[m] / (sqrtf(d2) + 1.0f);
  float mx = logit;
  #pragma unroll
  for (int off = 16; off > 0; off >>= 1) mx = fmaxf(mx, __shfl_xor(mx, off, 64));
  float e = __expf(logit - mx);
  float s = e;
  #pragma unroll
  for (int off = 16; off > 0; off >>= 1) s += __shfl_xor(s, off, 64);
  sim[(long)row * MODES + m] = e / s;

  // cast this row of x (128 floats) to bf16: 32 lanes x 4 elems
  const float4 xv = *(const float4*)(x + (long)row * DDIM + m * 4);
  ushort4 o;
  o.x = f2bf(xv.x); o.y = f2bf(xv.y); o.z = f2bf(xv.z); o.w = f2bf(xv.w);
  *(ushort4*)(x16 + (long)row * DDIM + m * 4) = o;
}

// ---------------------------------------------------------------------------
// Kernel 2: cast kernels + biases to bf16 in MFMA-B swizzled layout:
//   kb16[m][kblk][u][j] = kernels[m][kblk*8+j][u]   (kblk = k>>3, j = k&7)
//   bb16[kblk][u][j]    = biases[kblk*8+j][u]
// This makes each B-fragment (8 k-consecutive bf16 for one column) a
// contiguous 16B chunk -> ds_read_b128 in the GEMM, and makes the staging
// global_load_lds(width=16) compatible (flat contiguous copy).
// ---------------------------------------------------------------------------
__global__ __launch_bounds__(256) void prep_wb(
    const float* __restrict__ kernels, const float* __restrict__ biases,
    unsigned short* __restrict__ kb16, unsigned short* __restrict__ bb16) {
  int t = blockIdx.x * 256 + threadIdx.x;
  if (t < MODES * 16 * UDIM) {  // 65536 chunks of 8
    int u = t & 127, kb = (t >> 7) & 15, m = t >> 11;
    const float* src = kernels + (long)((m * 16 + kb) * 8) * UDIM + u;
    ushort4 lo, hi;
    lo.x = f2bf(src[0 * UDIM]); lo.y = f2bf(src[1 * UDIM]);
    lo.z = f2bf(src[2 * UDIM]); lo.w = f2bf(src[3 * UDIM]);
    hi.x = f2bf(src[4 * UDIM]); hi.y = f2bf(src[5 * UDIM]);
    hi.z = f2bf(src[6 * UDIM]); hi.w = f2bf(src[7 * UDIM]);
    *(ushort4*)(kb16 + (long)t * 8) = lo;
    *(ushort4*)(kb16 + (long)t * 8 + 4) = hi;
  } else if (t < MODES * 16 * UDIM + 4 * UDIM) {
    int tb = t - MODES * 16 * UDIM;
    int u = tb & 127, kb = tb >> 7;
    const float* src = biases + kb * 8 * UDIM + u;
    ushort4 lo, hi;
    lo.x = f2bf(src[0 * UDIM]); lo.y = f2bf(src[1 * UDIM]);
    lo.z = f2bf(src[2 * UDIM]); lo.w = f2bf(src[3 * UDIM]);
    hi.x = f2bf(src[4 * UDIM]); hi.y = f2bf(src[5 * UDIM]);
    hi.z = f2bf(src[6 * UDIM]); hi.w = f2bf(src[7 * UDIM]);
    *(ushort4*)(bb16 + (long)tb * 8) = lo;
    *(ushort4*)(bb16 + (long)tb * 8 + 4) = hi;
  }
}

// ---------------------------------------------------------------------------
// Kernel 3: the GEMM.  out[b,u] = (1/32)( sum_m sim[b,m]*(x[b,:]@K_m) + sim@biases )
// Block tile 128x128, 4 waves (2x2) of 64x64.  grid = (128 row-tiles, 4 mode-splits);
// each block handles 8 modes, fp32 atomicAdd epilogue (out pre-zeroed).
// X fragments live in registers across all modes; per mode: stage K_m (32KB)
// via global_load_lds, MFMA into a per-row-tile temp, then acc += sim_row*temp.
// ---------------------------------------------------------------------------
__global__ __launch_bounds__(256, 2) void gemm_poly(
    const unsigned short* __restrict__ x16, const unsigned short* __restrict__ kb16,
    const unsigned short* __restrict__ bb16, const float* __restrict__ sim,
    float* __restrict__ out) {
  __shared__ alignas(16) unsigned short bsh[16 * UDIM * 8];  // 32KB: [kblk 16][u 128][j 8]
  __shared__ alignas(16) float simT[8][128];                 // [mode_local][row]

  const int t = threadIdx.x;
  const int lane = t & 63, w = t >> 6;
  const int q = lane >> 4, l16 = lane & 15;
  const int wrow = (w >> 1) * 64, wcol = (w & 1) * 64;
  const long bm = (long)blockIdx.x * 128;
  const int split = blockIdx.y;  // 0..3, modes [split*8, split*8+8)

  // stage sim (own 8 modes, 128 rows) transposed into LDS
  {
    int rrow = t >> 1, mg = (t & 1) * 4;
    const float4 v = *(const float4*)(sim + (bm + rrow) * MODES + split * 8 + mg);
    simT[mg + 0][rrow] = v.x; simT[mg + 1][rrow] = v.y;
    simT[mg + 2][rrow] = v.z; simT[mg + 3][rrow] = v.w;
  }

  // A fragments (x, bf16) straight from global -> registers, once.
  // A[row = l16 + rt*16][k = ks*32 + q*8 + j] : contiguous 16B per frag.
  bf16x8 aF[4][4];
  #pragma unroll
  for (int rt = 0; rt < 4; ++rt)
    #pragma unroll
    for (int ks = 0; ks < 4; ++ks)
      aF[rt][ks] = *(const bf16x8*)(x16 + (bm + wrow + rt * 16 + l16) * DDIM + ks * 32 + q * 8);

  f32x4 acc[4][4] = {};  // [rt][ct]

  for (int mi = 0; mi < 8; ++mi) {
    const int m = split * 8 + mi;
    __syncthreads();  // previous-iter bF reads done (and simT staged, iter 0)
    const unsigned short* src = kb16 + (long)m * (16 * UDIM * 8);
    #pragma unroll
    for (int i = 0; i < 8; ++i) {
      int off = (t + i * 256) * 8;  // elements; *2 bytes = lane*16B pattern
      gld_lds16(src + off, bsh + off);
    }
    __syncthreads();  // vmcnt(0) drain: LDS tile complete

    // B fragments: [ks][ct], each contiguous 16B, conflict-free b128 reads
    bf16x8 bF[4][4];
    #pragma unroll
    for (int ks = 0; ks < 4; ++ks)
      #pragma unroll
      for (int ct = 0; ct < 4; ++ct)
        bF[ks][ct] = *(const bf16x8*)&bsh[(((ks * 4 + q) * UDIM) + wcol + ct * 16 + l16) * 8];

    #pragma unroll
    for (int rt = 0; rt < 4; ++rt) {
      f32x4 tmp[4] = {};
      #pragma unroll
      for (int ks = 0; ks < 4; ++ks)
        #pragma unroll
        for (int ct = 0; ct < 4; ++ct)
          tmp[ct] = __builtin_amdgcn_mfma_f32_16x16x32_bf16(aF[rt][ks], bF[ks][ct], tmp[ct], 0, 0, 0);
      // per-row sim scale: C/D rows are reg-consecutive -> one float4 per rt
      const f32x4 s = *(const f32x4*)&simT[mi][wrow + rt * 16 + q * 4];
      #pragma unroll
      for (int ct = 0; ct < 4; ++ct)
        acc[rt][ct] += s * tmp[ct];
    }
  }

  // bias term: one K=32 MFMA round, A = sim (bf16), B = biases (bf16).
  // Only split 0 does it (covers all 32 modes).
  if (split == 0) {
    bf16x8 sF[4];
    #pragma unroll
    for (int rt = 0; rt < 4; ++rt) {
      const float* sp = sim + (bm + wrow + rt * 16 + l16) * MODES + q * 8;
      bf16x8 f;
      #pragma unroll
      for (int j = 0; j < 8; ++j) f[j] = (short)f2bf(sp[j]);
      sF[rt] = f;
    }
    #pragma unroll
    for (int ct = 0; ct < 4; ++ct) {
      bf16x8 bb = *(const bf16x8*)(bb16 + (long)(q * UDIM + wcol + ct * 16 + l16) * 8);
      #pragma unroll
      for (int rt = 0; rt < 4; ++rt)
        acc[rt][ct] = __builtin_amdgcn_mfma_f32_16x16x32_bf16(sF[rt], bb, acc[rt][ct], 0, 0, 0);
    }
  }

  // epilogue: scale by 1/MODES, atomic-accumulate across the 4 mode-splits
  #pragma unroll
  for (int rt = 0; rt < 4; ++rt)
    #pragma unroll
    for (int ct = 0; ct < 4; ++ct) {
      long row = bm + wrow + rt * 16 + q * 4;
      int col = wcol + ct * 16 + l16;
      #pragma unroll
      for (int r = 0; r < 4; ++r)
        atomicAdd(out + (row + r) * UDIM + col, acc[rt][ct][r] * (1.0f / MODES));
    }
}

extern "C" void kernel_launch(void* const* d_in, const int* in_sizes, int n_in,
                              void* d_out, int out_size, void* d_ws, size_t ws_size,
                              hipStream_t stream) {
  const float* key      = (const float*)d_in[0];
  const float* x        = (const float*)d_in[1];
  const float* sens     = (const float*)d_in[2];
  const float* keys_map = (const float*)d_in[3];
  const float* kernels  = (const float*)d_in[4];
  const float* biases   = (const float*)d_in[5];
  float* out = (float*)d_out;

  char* ws = (char*)d_ws;
  float*          sim  = (float*)ws;                    // 16384*32*4  = 2 MB
  unsigned short* x16  = (unsigned short*)(ws + (2u << 20));  // 16384*128*2 = 4 MB
  unsigned short* kb16 = (unsigned short*)(ws + (6u << 20));  // 32*128*128*2 = 1 MB
  unsigned short* bb16 = (unsigned short*)(ws + (7u << 20));  // 32*128*2 = 8 KB

  hipMemsetAsync(out, 0, (size_t)BATCH * UDIM * sizeof(float), stream);
  prep_sim_x<<<BATCH / 8, 256, 0, stream>>>(key, x, sens, keys_map, sim, x16);
  prep_wb<<<(MODES * 16 * UDIM + 4 * UDIM + 255) / 256, 256, 0, stream>>>(kernels, biases, kb16, bb16);
  gemm_poly<<<dim3(BATCH / 128, 4), 256, 0, stream>>>(x16, kb16, bb16, sim, out);
}

// Round 2
// 128.990 us; speedup vs baseline: 1.0148x; 1.0148x over previous
//
#include <hip/hip_runtime.h>

// Problem constants
#define BATCH 16384
#define KEYD  64
#define DDIM  128
#define UDIM  128
#define MODES 32

typedef __attribute__((ext_vector_type(8))) short bf16x8;   // 8 bf16 in 4 VGPRs
typedef __attribute__((ext_vector_type(4))) float f32x4;

__device__ __forceinline__ unsigned short f2bf(float f) {
  unsigned u = __float_as_uint(f);
  // round-to-nearest-even bf16
  unsigned r = (u + 0x7FFFu + ((u >> 16) & 1u)) >> 16;
  return (unsigned short)r;
}

__device__ __forceinline__ void gld_lds16(const void* g, void* l) {
  __builtin_amdgcn_global_load_lds(
      (const __attribute__((address_space(1))) unsigned int*)g,
      (__attribute__((address_space(3))) unsigned int*)l, 16, 0, 0);
}

// ---------------------------------------------------------------------------
// Kernel 1: per-row softmax similarity + x -> bf16 cast.
// 16 rows per block. Key rows staged to LDS once (coalesced float4), then
// each half-wave (32 lanes = 32 modes) reads its row via free same-address
// LDS broadcast; kmT reads are bank-consecutive (conflict-free).
// ---------------------------------------------------------------------------
__global__ __launch_bounds__(256) void prep_sim_x(
    const float* __restrict__ key, const float* __restrict__ x,
    const float* __restrict__ sens, const float* __restrict__ keys_map,
    float* __restrict__ sim, unsigned short* __restrict__ x16) {
  __shared__ float kmT[KEYD * MODES];  // [k][m]: lane-m reads are bank-consecutive
  __shared__ float kr[16][KEYD];       // 16 key rows
  const int t = threadIdx.x;
  for (int i = t; i < MODES * KEYD; i += 256) {
    int m = i >> 6, k = i & 63;
    kmT[k * MODES + m] = keys_map[i];
  }
  {  // stage 16 rows of key: 1024 floats = 256 threads x float4, coalesced
    const float4 v = *(const float4*)(key + (long)blockIdx.x * 16 * KEYD + t * 4);
    *(float4*)(&kr[0][0] + t * 4) = v;
  }
  __syncthreads();

  const int lane = t & 63, wave = t >> 6;
  const int half = lane >> 5, m = lane & 31;
  const float sv = sens[m];

  #pragma unroll
  for (int pass = 0; pass < 2; ++pass) {
    const int rl = pass * 8 + wave * 2 + half;
    const long row = (long)blockIdx.x * 16 + rl;

    float d2 = 0.f;
    #pragma unroll
    for (int k = 0; k < KEYD; ++k) {
      float diff = kr[rl][k] - kmT[k * MODES + m];
      d2 += diff * diff;
    }
    float logit = sv / (sqrtf(d2) + 1.0f);
    float mx = logit;
    #pragma unroll
    for (int off = 16; off > 0; off >>= 1) mx = fmaxf(mx, __shfl_xor(mx, off, 64));
    float e = __expf(logit - mx);
    float s = e;
    #pragma unroll
    for (int off = 16; off > 0; off >>= 1) s += __shfl_xor(s, off, 64);
    sim[row * MODES + m] = e / s;

    // cast this row of x (128 floats) to bf16: 32 lanes x 4 elems
    const float4 xv = *(const float4*)(x + row * DDIM + m * 4);
    ushort4 o;
    o.x = f2bf(xv.x); o.y = f2bf(xv.y); o.z = f2bf(xv.z); o.w = f2bf(xv.w);
    *(ushort4*)(x16 + row * DDIM + m * 4) = o;
  }
}

// ---------------------------------------------------------------------------
// Kernel 2: cast kernels + biases to bf16 in MFMA-B swizzled layout:
//   kb16[m][kblk][u][j] = kernels[m][kblk*8+j][u]   (kblk = k>>3, j = k&7)
//   bb16[kblk][u][j]    = biases[kblk*8+j][u]
// ---------------------------------------------------------------------------
__global__ __launch_bounds__(256) void prep_wb(
    const float* __restrict__ kernels, const float* __restrict__ biases,
    unsigned short* __restrict__ kb16, unsigned short* __restrict__ bb16) {
  int t = blockIdx.x * 256 + threadIdx.x;
  if (t < MODES * 16 * UDIM) {  // 65536 chunks of 8
    int u = t & 127, kb = (t >> 7) & 15, m = t >> 11;
    const float* src = kernels + (long)((m * 16 + kb) * 8) * UDIM + u;
    ushort4 lo, hi;
    lo.x = f2bf(src[0 * UDIM]); lo.y = f2bf(src[1 * UDIM]);
    lo.z = f2bf(src[2 * UDIM]); lo.w = f2bf(src[3 * UDIM]);
    hi.x = f2bf(src[4 * UDIM]); hi.y = f2bf(src[5 * UDIM]);
    hi.z = f2bf(src[6 * UDIM]); hi.w = f2bf(src[7 * UDIM]);
    *(ushort4*)(kb16 + (long)t * 8) = lo;
    *(ushort4*)(kb16 + (long)t * 8 + 4) = hi;
  } else if (t < MODES * 16 * UDIM + 4 * UDIM) {
    int tb = t - MODES * 16 * UDIM;
    int u = tb & 127, kb = tb >> 7;
    const float* src = biases + kb * 8 * UDIM + u;
    ushort4 lo, hi;
    lo.x = f2bf(src[0 * UDIM]); lo.y = f2bf(src[1 * UDIM]);
    lo.z = f2bf(src[2 * UDIM]); lo.w = f2bf(src[3 * UDIM]);
    hi.x = f2bf(src[4 * UDIM]); hi.y = f2bf(src[5 * UDIM]);
    hi.z = f2bf(src[6 * UDIM]); hi.w = f2bf(src[7 * UDIM]);
    *(ushort4*)(bb16 + (long)tb * 8) = lo;
    *(ushort4*)(bb16 + (long)tb * 8 + 4) = hi;
  }
}

// ---------------------------------------------------------------------------
// Kernel 3: the GEMM.  out[b,u] = (1/32)( sum_m sim[b,m]*(x[b,:]@K_m) + sim@biases )
// Block tile 128x128, 4 waves (2x2) of 64x64. grid = (128 row-tiles, 4 splits).
// DOUBLE-BUFFERED B staging: one barrier per mode; the global_load_lds for
// mode mi+1 is issued right after the barrier opening mode mi, so its
// vmcnt(0) drain (at the next barrier) overlaps the full MFMA phase.
// ---------------------------------------------------------------------------
__global__ __launch_bounds__(256, 2) void gemm_poly(
    const unsigned short* __restrict__ x16, const unsigned short* __restrict__ kb16,
    const unsigned short* __restrict__ bb16, const float* __restrict__ sim,
    float* __restrict__ out) {
  __shared__ alignas(16) unsigned short bsh[2][16 * UDIM * 8];  // 2 x 32KB
  __shared__ alignas(16) float simT[8][128];                    // [mode_local][row]

  const int t = threadIdx.x;
  const int lane = t & 63, w = t >> 6;
  const int q = lane >> 4, l16 = lane & 15;
  const int wrow = (w >> 1) * 64, wcol = (w & 1) * 64;
  const long bm = (long)blockIdx.x * 128;
  const int split = blockIdx.y;  // 0..3, modes [split*8, split*8+8)

  // stage sim (own 8 modes, 128 rows) transposed into LDS
  {
    int rrow = t >> 1, mg = (t & 1) * 4;
    const float4 v = *(const float4*)(sim + (bm + rrow) * MODES + split * 8 + mg);
    simT[mg + 0][rrow] = v.x; simT[mg + 1][rrow] = v.y;
    simT[mg + 2][rrow] = v.z; simT[mg + 3][rrow] = v.w;
  }

  // A fragments (x, bf16) straight from global -> registers, once.
  bf16x8 aF[4][4];
  #pragma unroll
  for (int rt = 0; rt < 4; ++rt)
    #pragma unroll
    for (int ks = 0; ks < 4; ++ks)
      aF[rt][ks] = *(const bf16x8*)(x16 + (bm + wrow + rt * 16 + l16) * DDIM + ks * 32 + q * 8);

  // stage mode m into bsh[buf] (flat 32KB copy, lane*16B pattern)
  const unsigned short* kbase = kb16 + (long)(split * 8) * (16 * UDIM * 8);
  #pragma unroll
  for (int i = 0; i < 8; ++i) {
    int off = (t + i * 256) * 8;
    gld_lds16(kbase + off, &bsh[0][off]);
  }

  f32x4 acc[4][4] = {};  // [rt][ct]

  for (int mi = 0; mi < 8; ++mi) {
    __syncthreads();  // drains own vmcnt: bsh[mi&1] staged; prev reads done
    if (mi < 7) {     // prefetch next mode into the other buffer
      const unsigned short* src = kbase + (long)(mi + 1) * (16 * UDIM * 8);
      unsigned short* dst = bsh[(mi + 1) & 1];
      #pragma unroll
      for (int i = 0; i < 8; ++i) {
        int off = (t + i * 256) * 8;
        gld_lds16(src + off, dst + off);
      }
    }

    const unsigned short* bs = bsh[mi & 1];
    // B fragments: [ks][ct], each contiguous 16B, conflict-free b128 reads
    bf16x8 bF[4][4];
    #pragma unroll
    for (int ks = 0; ks < 4; ++ks)
      #pragma unroll
      for (int ct = 0; ct < 4; ++ct)
        bF[ks][ct] = *(const bf16x8*)&bs[(((ks * 4 + q) * UDIM) + wcol + ct * 16 + l16) * 8];

    #pragma unroll
    for (int rt = 0; rt < 4; ++rt) {
      f32x4 tmp[4] = {};
      #pragma unroll
      for (int ks = 0; ks < 4; ++ks)
        #pragma unroll
        for (int ct = 0; ct < 4; ++ct)
          tmp[ct] = __builtin_amdgcn_mfma_f32_16x16x32_bf16(aF[rt][ks], bF[ks][ct], tmp[ct], 0, 0, 0);
      // per-row sim scale: C/D rows are reg-consecutive -> one float4 per rt
      const f32x4 s = *(const f32x4*)&simT[mi][wrow + rt * 16 + q * 4];
      #pragma unroll
      for (int ct = 0; ct < 4; ++ct)
        acc[rt][ct] += s * tmp[ct];
    }
  }

  // bias term: one K=32 MFMA round, A = sim (bf16), B = biases (bf16).
  // Only split 0 does it (covers all 32 modes).
  if (split == 0) {
    bf16x8 sF[4];
    #pragma unroll
    for (int rt = 0; rt < 4; ++rt) {
      const float* sp = sim + (bm + wrow + rt * 16 + l16) * MODES + q * 8;
      bf16x8 f;
      #pragma unroll
      for (int j = 0; j < 8; ++j) f[j] = (short)f2bf(sp[j]);
      sF[rt] = f;
    }
    #pragma unroll
    for (int ct = 0; ct < 4; ++ct) {
      bf16x8 bb = *(const bf16x8*)(bb16 + (long)(q * UDIM + wcol + ct * 16 + l16) * 8);
      #pragma unroll
      for (int rt = 0; rt < 4; ++rt)
        acc[rt][ct] = __builtin_amdgcn_mfma_f32_16x16x32_bf16(sF[rt], bb, acc[rt][ct], 0, 0, 0);
    }
  }

  // epilogue: scale by 1/MODES, atomic-accumulate across the 4 mode-splits
  #pragma unroll
  for (int rt = 0; rt < 4; ++rt)
    #pragma unroll
    for (int ct = 0; ct < 4; ++ct) {
      long row = bm + wrow + rt * 16 + q * 4;
      int col = wcol + ct * 16 + l16;
      #pragma unroll
      for (int r = 0; r < 4; ++r)
        atomicAdd(out + (row + r) * UDIM + col, acc[rt][ct][r] * (1.0f / MODES));
    }
}

extern "C" void kernel_launch(void* const* d_in, const int* in_sizes, int n_in,
                              void* d_out, int out_size, void* d_ws, size_t ws_size,
                              hipStream_t stream) {
  const float* key      = (const float*)d_in[0];
  const float* x        = (const float*)d_in[1];
  const float* sens     = (const float*)d_in[2];
  const float* keys_map = (const float*)d_in[3];
  const float* kernels  = (const float*)d_in[4];
  const float* biases   = (const float*)d_in[5];
  float* out = (float*)d_out;

  char* ws = (char*)d_ws;
  float*          sim  = (float*)ws;                          // 16384*32*4  = 2 MB
  unsigned short* x16  = (unsigned short*)(ws + (2u << 20));  // 16384*128*2 = 4 MB
  unsigned short* kb16 = (unsigned short*)(ws + (6u << 20));  // 32*128*128*2 = 1 MB
  unsigned short* bb16 = (unsigned short*)(ws + (7u << 20));  // 32*128*2 = 8 KB

  hipMemsetAsync(out, 0, (size_t)BATCH * UDIM * sizeof(float), stream);
  prep_sim_x<<<BATCH / 16, 256, 0, stream>>>(key, x, sens, keys_map, sim, x16);
  prep_wb<<<(MODES * 16 * UDIM + 4 * UDIM + 255) / 256, 256, 0, stream>>>(kernels, biases, kb16, bb16);
  gemm_poly<<<dim3(BATCH / 128, 4), 256, 0, stream>>>(x16, kb16, bb16, sim, out);
}